// Round 11
// baseline (521.604 us; speedup 1.0000x reference)
//
#include <hip/hip_runtime.h>
#include <hip/hip_bf16.h>
#include <math.h>

#define LN 4
#define B_ 8
#define D_ 2048
#define DI 4096
#define N_ 128
#define H_ 64
#define P_ 64
#define K_ 4
#define M_ 8
#define V_ 50288
#define CCH (DI + 2*N_)           // 4352
#define DOUT (2*DI + 2*N_ + H_)   // 8512
#define EPSF 1e-5f
#define KT_IN 32                  // in_proj k-tiles (k0=64)
#define KT_OUT 128                // out_proj k-tiles (k0=32)
#define NJ4 (DOUT / 4)            // 2128 f32x4 columns
#define JTW 266                   // f32x4 cols per jt tile (8 tiles)

typedef float f32x4 __attribute__((ext_vector_type(4)));

__device__ inline float wave_sum(float v) {
  #pragma unroll
  for (int off = 32; off > 0; off >>= 1) v += __shfl_xor(v, off, 64);
  return v;
}

// Fold-reduce 8 per-lane accumulators: lane l gets full 64-lane sum of a[l&7].
__device__ inline float fold_reduce8(const float a[8], int lane) {
  float t0[4];
  #pragma unroll
  for (int r = 0; r < 4; ++r) {
    float keep = (lane & 1) ? a[2*r+1] : a[2*r];
    float send = (lane & 1) ? a[2*r]   : a[2*r+1];
    t0[r] = keep + __shfl_xor(send, 1, 64);
  }
  float t1[2];
  #pragma unroll
  for (int r = 0; r < 2; ++r) {
    float keep = (lane & 2) ? t0[2*r+1] : t0[2*r];
    float send = (lane & 2) ? t0[2*r]   : t0[2*r+1];
    t1[r] = keep + __shfl_xor(send, 2, 64);
  }
  float keep = (lane & 4) ? t1[1] : t1[0];
  float send = (lane & 4) ? t1[0] : t1[1];
  float u = keep + __shfl_xor(send, 4, 64);
  u += __shfl_xor(u, 8, 64);
  u += __shfl_xor(u, 16, 64);
  u += __shfl_xor(u, 32, 64);
  return u;
}

// ------- prenorm (once): embed gather -> res, ssq_in[b] = sum(res^2) ---------
__global__ __launch_bounds__(256)
void k_prenorm(const int* __restrict__ ids, const float* __restrict__ emb,
               float* __restrict__ res, float* __restrict__ ssq_in) {
  __shared__ float lds[4];
  int b = blockIdx.x, tid = threadIdx.x;
  const float* row = emb + (size_t)ids[b] * D_;
  f32x4 v0 = *reinterpret_cast<const f32x4*>(row + tid * 8);
  f32x4 v1 = *reinterpret_cast<const f32x4*>(row + tid * 8 + 4);
  *reinterpret_cast<f32x4*>(res + (size_t)b * D_ + tid * 8)     = v0;
  *reinterpret_cast<f32x4*>(res + (size_t)b * D_ + tid * 8 + 4) = v1;
  float ss = v0[0]*v0[0] + v0[1]*v0[1] + v0[2]*v0[2] + v0[3]*v0[3]
           + v1[0]*v1[0] + v1[1]*v1[1] + v1[2]*v1[2] + v1[3]*v1[3];
  float wsum = wave_sum(ss);
  int lane = tid & 63, wid = tid >> 6;
  if (lane == 0) lds[wid] = wsum;
  __syncthreads();
  if (tid == 0) ssq_in[b] = lds[0] + lds[1] + lds[2] + lds[3];
}

// ------ in_proj stage 1: grid EXACTLY 256 (8 jt x 32 kt), 256 threads --------
// jt tile = 266 f32x4 cols; threads 0..9 carry a second column (cols 256..265)
// interleaved in the same kk loop. Norm fused via precomputed ssq_in.
__global__ __launch_bounds__(256)
void k_inproj1(const float* __restrict__ res, const float* __restrict__ ssq_in,
               const float* __restrict__ lnw, const float* __restrict__ W,
               float* __restrict__ pin) {
  __shared__ float xs[8][64];
  int tid = threadIdx.x;
  int jt = blockIdx.x & 7, kt = blockIdx.x >> 3;
  int k0 = kt * 64;
  for (int i = tid; i < 8 * 64; i += 256) {
    int r = i >> 6, kk = i & 63;
    float scale = rsqrtf(ssq_in[r] / (float)D_ + EPSF);
    xs[r][kk] = res[r * D_ + k0 + kk] * scale * lnw[k0 + kk];
  }
  __syncthreads();
  int j4  = jt * JTW + tid;         // first f32x4 column (always valid)
  bool two = (tid < JTW - 256);     // 10 threads carry a second column
  int j4b = j4 + 256;
  f32x4 acc[8], accb[8];
  #pragma unroll
  for (int r = 0; r < 8; ++r) { acc[r] = (f32x4)0.f; accb[r] = (f32x4)0.f; }
  const f32x4* W4 = reinterpret_cast<const f32x4*>(W) + (size_t)k0 * NJ4;
  for (int kk = 0; kk < 64; ++kk) {
    f32x4 w4 = __builtin_nontemporal_load(&W4[(size_t)kk * NJ4 + j4]);
    #pragma unroll
    for (int r = 0; r < 8; ++r) acc[r] += w4 * xs[r][kk];
    if (two) {
      f32x4 w4b = __builtin_nontemporal_load(&W4[(size_t)kk * NJ4 + j4b]);
      #pragma unroll
      for (int r = 0; r < 8; ++r) accb[r] += w4b * xs[r][kk];
    }
  }
  #pragma unroll
  for (int r = 0; r < 8; ++r)
    reinterpret_cast<f32x4*>(pin)[((size_t)kt * 8 + r) * NJ4 + j4] = acc[r];
  if (two) {
    #pragma unroll
    for (int r = 0; r < 8; ++r)
      reinterpret_cast<f32x4*>(pin)[((size_t)kt * 8 + r) * NJ4 + j4b] = accb[r];
  }
}

// ------- in_proj stage 2: reduce partials -> zx, fused conv+dt+softmax -------
__global__ __launch_bounds__(256)
void k_inproj2_conv(const float* __restrict__ pin, const float* __restrict__ conv_state,
                    const float* __restrict__ conv_w, const float* __restrict__ conv_b,
                    const float* __restrict__ A_log, const float* __restrict__ dt_bias,
                    const float* __restrict__ W_mc,
                    float* __restrict__ zx, float* __restrict__ xbc,
                    float* __restrict__ dts, float* __restrict__ dav,
                    float* __restrict__ wmc) {
  const int TOT4 = B_ * DOUT / 4;   // 17024
  int t = blockIdx.x * 256 + threadIdx.x;
  if (t >= TOT4) return;
  f32x4 s = (f32x4)0.f;
  const f32x4* p4 = reinterpret_cast<const f32x4*>(pin) + t;
  #pragma unroll 8
  for (int kt = 0; kt < KT_IN; ++kt) s += p4[(size_t)kt * TOT4];
  reinterpret_cast<f32x4*>(zx)[t] = s;
  int c4 = t * 4;
  int b = c4 / DOUT;
  int c = c4 - b * DOUT;
  #pragma unroll
  for (int e = 0; e < 4; ++e) {
    int ce = c + e;
    if (ce >= DI && ce < DI + CCH) {
      int cc = ce - DI;
      f32x4 cs4 = *reinterpret_cast<const f32x4*>(conv_state + ((size_t)b * CCH + cc) * K_);
      f32x4 cw4 = *reinterpret_cast<const f32x4*>(conv_w + (size_t)cc * K_);
      float v = cs4[1] * cw4[0] + cs4[2] * cw4[1] + cs4[3] * cw4[2]
              + s[e] * cw4[3] + conv_b[cc];
      xbc[b * CCH + cc] = v / (1.f + expf(-v));   // silu
    } else if (ce >= DI + CCH) {
      int h = ce - DI - CCH;
      float x = s[e] + dt_bias[h];
      float sp = (x > 20.f) ? x : log1pf(expf(x));  // softplus
      dts[b * 64 + h] = sp;
      dav[b * 64 + h] = expf(-expf(A_log[h]) * sp);
    }
  }
  if (t == 0) {
    float mx = -1e30f;
    for (int i = 0; i < M_ + 1; ++i) mx = fmaxf(mx, W_mc[i]);
    float e2[M_ + 1], sum = 0.f;
    for (int i = 0; i < M_ + 1; ++i) { e2[i] = expf(W_mc[i] - mx); sum += e2[i]; }
    for (int i = 0; i < M_ + 1; ++i) wmc[i] = e2[i] / sum;
  }
}

// ---------------- state update + MC fuse + y (R10-exact) ---------------------
__global__ __launch_bounds__(256)
void k_state(const float* __restrict__ xbc, const float* __restrict__ dts,
             const float* __restrict__ dav, const float* __restrict__ Dp_,
             const float* __restrict__ wmc, const float* __restrict__ ssm,
             const float* __restrict__ cached, float* __restrict__ y) {
  int wg = blockIdx.x * 4 + (threadIdx.x >> 6);   // [0, 16384)
  int lane = threadIdx.x & 63;
  int b = wg >> 11;
  int h = (wg >> 5) & 63;
  int pp = wg & 31;
  int hf = lane >> 5, il = lane & 31;
  int p = pp * 2 + hf;
  float xv  = xbc[b * CCH + h * 64 + p];
  float dtv = dts[b * 64 + h];
  float da  = dav[b * 64 + h];
  float w8  = wmc[8];
  const f32x4* xb4 = reinterpret_cast<const f32x4*>(xbc);
  f32x4 B4 = xb4[b * (CCH / 4) + DI / 4 + il];
  f32x4 C4 = xb4[b * (CCH / 4) + DI / 4 + N_ / 4 + il];
  const f32x4* sp4 = reinterpret_cast<const f32x4*>(ssm) +
                     ((size_t)((b * H_ + h) * P_ + p)) * (N_ / 4) + il;
  const f32x4* cp4 = reinterpret_cast<const f32x4*>(cached) +
                     ((size_t)(((b * M_) * H_ + h) * P_ + p)) * (N_ / 4) + il;
  f32x4 s4 = __builtin_nontemporal_load(sp4);
  f32x4 f4 = (s4 * da + B4 * (dtv * xv)) * w8;
  #pragma unroll
  for (int m = 0; m < 8; ++m) {
    f32x4 c4 = __builtin_nontemporal_load(cp4 + (size_t)m * (H_ * P_ * N_ / 4));
    f4 += c4 * wmc[m];
  }
  f4 *= C4;
  float acc = f4[0] + f4[1] + f4[2] + f4[3];
  #pragma unroll
  for (int off = 1; off < 32; off <<= 1) acc += __shfl_xor(acc, off, 64);
  if (il == 0) y[b * DI + h * 64 + p] = acc + Dp_[h] * xv;
}

// ------ out_proj stage 1 with FUSED gated-RMS-norm (redundant prologue) ------
// Each block recomputes the 8 row-ssq of v = y*silu(z) (L2-hot reads), then
// stages its 32-wide k-slice of v*rsqrt(ssq/DI+eps)*mnw. Zeroes ssq_in (blk 0).
__global__ __launch_bounds__(256)
void k_outproj1(const float* __restrict__ y, const float* __restrict__ zx,
                const float* __restrict__ mnw, const float* __restrict__ W,
                float* __restrict__ pout, float* __restrict__ ssq_in) {
  __shared__ float xs[8][32];
  __shared__ float sred[4][8];
  int tid = threadIdx.x, lane = tid & 63, wid = tid >> 6;
  if (blockIdx.x == 0 && tid < 8) ssq_in[tid] = 0.f;
  const f32x4* y4 = reinterpret_cast<const f32x4*>(y);
  const f32x4* z4 = reinterpret_cast<const f32x4*>(zx);
  #pragma unroll
  for (int r = 0; r < 8; ++r) {
    float s = 0.f;
    #pragma unroll
    for (int t = 0; t < 4; ++t) {
      int q = tid + t * 256;
      f32x4 yv = y4[r * (DI / 4) + q];
      f32x4 zv = z4[r * (DOUT / 4) + q];
      #pragma unroll
      for (int e = 0; e < 4; ++e) {
        float g = zv[e] / (1.f + expf(-zv[e]));
        float v = yv[e] * g;
        s += v * v;
      }
    }
    float wsum = wave_sum(s);
    if (lane == 0) sred[wid][r] = wsum;
  }
  __syncthreads();
  int jt = blockIdx.x & 1, kt = blockIdx.x >> 1;
  int k0 = kt * 32;
  {
    int r = tid >> 5, kk = tid & 31;
    float tot = sred[0][r] + sred[1][r] + sred[2][r] + sred[3][r];
    float scale = rsqrtf(tot / (float)DI + EPSF);
    float z = zx[r * DOUT + k0 + kk];
    float g = z / (1.f + expf(-z));
    xs[r][kk] = y[r * DI + k0 + kk] * g * scale * mnw[k0 + kk];
  }
  __syncthreads();
  int j = jt * 1024 + tid * 4;
  f32x4 acc[8];
  #pragma unroll
  for (int r = 0; r < 8; ++r) acc[r] = (f32x4)0.f;
  const float* Wp = W + (size_t)k0 * D_ + j;
  for (int kk = 0; kk < 32; ++kk) {
    f32x4 w4 = __builtin_nontemporal_load(
        reinterpret_cast<const f32x4*>(Wp + (size_t)kk * D_));
    #pragma unroll
    for (int r = 0; r < 8; ++r) acc[r] += w4 * xs[r][kk];
  }
  #pragma unroll
  for (int r = 0; r < 8; ++r)
    *reinterpret_cast<f32x4*>(&pout[((size_t)kt * 8 + r) * D_ + j]) = acc[r];
}

// ------- out_proj stage 2: reduce partials, res += (single writer);
// ------- accumulates next-norm ssq_in[row] from the res it just wrote.
__global__ __launch_bounds__(256)
void k_outproj2(const float* __restrict__ pout, float* __restrict__ res,
                float* __restrict__ ssq_in) {
  __shared__ f32x4 red[256];
  const int TOT4 = B_ * D_ / 4;   // 4096
  int tid = threadIdx.x;
  int pos = blockIdx.x * 64 + (tid & 63);
  int kq = tid >> 6;              // wave index = kt quarter
  const f32x4* p4 = reinterpret_cast<const f32x4*>(pout) + pos;
  f32x4 s = (f32x4)0.f;
  #pragma unroll 8
  for (int k = 0; k < 32; ++k)
    s += p4[(size_t)(kq * 32 + k) * TOT4];
  red[tid] = s;
  __syncthreads();
  if (tid < 64) {
    f32x4 tot = red[tid] + red[tid + 64] + red[tid + 128] + red[tid + 192];
    f32x4* r4 = reinterpret_cast<f32x4*>(res);
    f32x4 nv = r4[pos] + tot;
    r4[pos] = nv;
    float ps = nv[0]*nv[0] + nv[1]*nv[1] + nv[2]*nv[2] + nv[3]*nv[3];
    ps = wave_sum(ps);
    if (tid == 0) atomicAdd(&ssq_in[pos >> 9], ps);
  }
}

// ---------------- logits: wave-per-row, split-D (SL=4), FUSED final norm -----
#define SL_ 4
#define KS_ (D_ / SL_)            // 512
#define NVB16 (V_ / 16)           // 3143 (exact)
__global__ __launch_bounds__(256)
void k_logits(const float* __restrict__ res, const float* __restrict__ ssq_in,
              const float* __restrict__ nfw, const float* __restrict__ emb,
              float* __restrict__ pl) {
  __shared__ f32x4 xs[8][KS_ / 4];   // 16 KB -> 8 blocks/CU, 32 waves/CU
  int s = blockIdx.x & 3, vb = blockIdx.x >> 2;
  const f32x4* res4 = reinterpret_cast<const f32x4*>(res);
  const f32x4* nfw4 = reinterpret_cast<const f32x4*>(nfw);
  for (int i = threadIdx.x; i < 8 * (KS_ / 4); i += 256) {
    int r = i >> 7, q = i & 127;
    float scale = rsqrtf(ssq_in[r] / (float)D_ + EPSF);
    xs[r][q] = res4[r * (D_ / 4) + s * (KS_ / 4) + q] * scale
             * nfw4[s * (KS_ / 4) + q];
  }
  __syncthreads();
  int wid = threadIdx.x >> 6, lane = threadIdx.x & 63;
  int v0 = vb * 16 + wid * 4;
  const f32x4* e4 = reinterpret_cast<const f32x4*>(emb);
  #pragma unroll
  for (int vv = 0; vv < 4; ++vv) {
    int v = v0 + vv;
    const f32x4* ep = e4 + (size_t)v * (D_ / 4) + s * (KS_ / 4);
    float acc[8] = {0,0,0,0,0,0,0,0};
    #pragma unroll
    for (int st = 0; st < KS_ / 256; ++st) {
      int c = st * 64 + lane;
      f32x4 e = __builtin_nontemporal_load(ep + c);
      #pragma unroll
      for (int r = 0; r < 8; ++r) {
        f32x4 x = xs[r][c];
        acc[r] += e[0]*x[0] + e[1]*x[1] + e[2]*x[2] + e[3]*x[3];
      }
    }
    float u = fold_reduce8(acc, lane);
    if (lane < 8) pl[((size_t)s * 8 + lane) * V_ + v] = u;
  }
}

// ---------------- logits combine: out = sum of 4 slice partials --------------
__global__ __launch_bounds__(256)
void k_logits2(const float* __restrict__ pl, float* __restrict__ out) {
  int v = blockIdx.x * 256 + threadIdx.x;
  if (v >= V_) return;
  int r = blockIdx.y;
  float t = pl[(size_t)r * V_ + v]
          + pl[((size_t)8  + r) * V_ + v]
          + pl[((size_t)16 + r) * V_ + v]
          + pl[((size_t)24 + r) * V_ + v];
  out[(size_t)r * V_ + v] = t;
}

extern "C" void kernel_launch(void* const* d_in, const int* in_sizes, int n_in,
                              void* d_out, int out_size, void* d_ws, size_t ws_size,
                              hipStream_t stream) {
  const int*   ids    = (const int*)  d_in[0];
  const float* emb    = (const float*)d_in[1];
  const float* inW    = (const float*)d_in[2];
  const float* convW  = (const float*)d_in[3];
  const float* convB  = (const float*)d_in[4];
  const float* Alog   = (const float*)d_in[5];
  const float* dtB    = (const float*)d_in[6];
  const float* Dpar   = (const float*)d_in[7];
  const float* mnw    = (const float*)d_in[8];
  const float* outW   = (const float*)d_in[9];
  const float* lnw    = (const float*)d_in[10];
  const float* nfw    = (const float*)d_in[11];
  const float* Wmc    = (const float*)d_in[12];
  const float* convS  = (const float*)d_in[13];
  const float* ssmS   = (const float*)d_in[14];
  const float* cached = (const float*)d_in[15];
  float* out = (float*)d_out;
  float* ws  = (float*)d_ws;

  float* res   = ws;            // 16384 floats
  float* zx    = ws + 16384;    // 68096
  float* xbc   = ws + 84480;    // 34816
  float* dts   = ws + 119296;   // 512
  float* dav   = ws + 119808;   // 512
  float* wmc   = ws + 120320;   // 64
  float* ssqi  = ws + 120384;   // 64 (8 used)
  float* y     = ws + 120448;   // 32768
  float* pin   = ws + 153216;   // 32*8*8512 = 2179072
  float* pout  = ws + 2332288;  // 128*8*2048 = 2097152
  float* pl    = ws + 4429440;  // 4*8*50288 = 1609216 -> ends 6038656 (~24.2MB)

  k_prenorm<<<8, 256, 0, stream>>>(ids, emb, res, ssqi);
  for (int l = 0; l < LN; ++l) {
    k_inproj1<<<256, 256, 0, stream>>>(res, ssqi, lnw + (size_t)l * D_,
                                       inW + (size_t)l * D_ * DOUT, pin);
    k_inproj2_conv<<<67, 256, 0, stream>>>(pin,
        convS + (size_t)l * B_ * CCH * K_, convW + (size_t)l * CCH * K_,
        convB + (size_t)l * CCH, Alog + l * H_, dtB + l * H_, Wmc + l * (M_ + 1),
        zx, xbc, dts, dav, wmc);
    k_state<<<4096, 256, 0, stream>>>(xbc, dts, dav, Dpar + l * H_, wmc,
        ssmS + (size_t)l * B_ * H_ * P_ * N_,
        cached + (size_t)l * B_ * M_ * H_ * P_ * N_, y);
    k_outproj1<<<256, 256, 0, stream>>>(y, zx, mnw + (size_t)l * DI,
                                        outW + (size_t)l * DI * D_, pout, ssqi);
    k_outproj2<<<64, 256, 0, stream>>>(pout, res, ssqi);
  }
  k_logits<<<NVB16 * SL_, 256, 0, stream>>>(res, ssqi, nfw, emb, pl);
  k_logits2<<<dim3((V_ + 255) / 256, 8), 256, 0, stream>>>(pl, out);
}

// Round 12
// 427.422 us; speedup vs baseline: 1.2203x; 1.2203x over previous
//
#include <hip/hip_runtime.h>
#include <hip/hip_bf16.h>
#include <math.h>

#define LN 4
#define B_ 8
#define D_ 2048
#define DI 4096
#define N_ 128
#define H_ 64
#define P_ 64
#define K_ 4
#define M_ 8
#define V_ 50288
#define CCH (DI + 2*N_)           // 4352
#define DOUT (2*DI + 2*N_ + H_)   // 8512
#define EPSF 1e-5f
#define KT_IN 32                  // in_proj k-tiles (k0=64)
#define KT_OUT 128                // out_proj k-tiles (k0=32)

typedef float f32x4 __attribute__((ext_vector_type(4)));

__device__ inline float wave_sum(float v) {
  #pragma unroll
  for (int off = 32; off > 0; off >>= 1) v += __shfl_xor(v, off, 64);
  return v;
}

// Fold-reduce 8 per-lane accumulators: lane l gets full 64-lane sum of a[l&7].
__device__ inline float fold_reduce8(const float a[8], int lane) {
  float t0[4];
  #pragma unroll
  for (int r = 0; r < 4; ++r) {
    float keep = (lane & 1) ? a[2*r+1] : a[2*r];
    float send = (lane & 1) ? a[2*r]   : a[2*r+1];
    t0[r] = keep + __shfl_xor(send, 1, 64);
  }
  float t1[2];
  #pragma unroll
  for (int r = 0; r < 2; ++r) {
    float keep = (lane & 2) ? t0[2*r+1] : t0[2*r];
    float send = (lane & 2) ? t0[2*r]   : t0[2*r+1];
    t1[r] = keep + __shfl_xor(send, 2, 64);
  }
  float keep = (lane & 4) ? t1[1] : t1[0];
  float send = (lane & 4) ? t1[0] : t1[1];
  float u = keep + __shfl_xor(send, 4, 64);
  u += __shfl_xor(u, 8, 64);
  u += __shfl_xor(u, 16, 64);
  u += __shfl_xor(u, 32, 64);
  return u;
}

// ------ in_proj stage 1, LAYER 0: embed-gather + in-block rmsnorm prologue ---
// (R8-proven form: squares-only prologue, 288 blocks, 256 threads)
__global__ __launch_bounds__(256)
void k_inproj1_first(const int* __restrict__ ids, const float* __restrict__ emb,
                     const float* __restrict__ lnw, const float* __restrict__ W,
                     float* __restrict__ pin) {
  __shared__ float xs[8][64];
  __shared__ float sred[4][8];
  int tid = threadIdx.x, lane = tid & 63, wid = tid >> 6;
  int jt = blockIdx.x % 9, kt = blockIdx.x / 9;
  int k0 = kt * 64;
  float ssq[8];
  #pragma unroll
  for (int r = 0; r < 8; ++r) {
    const float* row = emb + (size_t)ids[r] * D_;
    f32x4 a = *reinterpret_cast<const f32x4*>(row + tid * 8);
    f32x4 c = *reinterpret_cast<const f32x4*>(row + tid * 8 + 4);
    ssq[r] = a[0]*a[0] + a[1]*a[1] + a[2]*a[2] + a[3]*a[3]
           + c[0]*c[0] + c[1]*c[1] + c[2]*c[2] + c[3]*c[3];
  }
  #pragma unroll
  for (int r = 0; r < 8; ++r) {
    float wsum = wave_sum(ssq[r]);
    if (lane == 0) sred[wid][r] = wsum;
  }
  __syncthreads();
  for (int i = tid; i < 8 * 64; i += 256) {
    int r = i >> 6, kk = i & 63;
    const float* row = emb + (size_t)ids[r] * D_;
    float tot = sred[0][r] + sred[1][r] + sred[2][r] + sred[3][r];
    float scale = rsqrtf(tot / (float)D_ + EPSF);
    xs[r][kk] = row[k0 + kk] * scale * lnw[k0 + kk];
  }
  __syncthreads();
  int j = jt * 1024 + tid * 4;
  if (j >= DOUT) return;
  f32x4 acc[8];
  #pragma unroll
  for (int r = 0; r < 8; ++r) acc[r] = (f32x4)0.f;
  const float* Wp = W + (size_t)k0 * DOUT + j;
  for (int kk = 0; kk < 64; ++kk) {
    f32x4 w4 = __builtin_nontemporal_load(
        reinterpret_cast<const f32x4*>(Wp + (size_t)kk * DOUT));
    #pragma unroll
    for (int r = 0; r < 8; ++r) acc[r] += w4 * xs[r][kk];
  }
  #pragma unroll
  for (int r = 0; r < 8; ++r)
    *reinterpret_cast<f32x4*>(&pin[((size_t)kt * 8 + r) * DOUT + j]) = acc[r];
}

// ------ in_proj stage 1, layers 1-3: R10 geometry (288 blocks), ssqi norm ----
__global__ __launch_bounds__(256)
void k_inproj1(const float* __restrict__ res, const float* __restrict__ ssq_in,
               const float* __restrict__ lnw, const float* __restrict__ W,
               float* __restrict__ pin) {
  __shared__ float xs[8][64];
  int tid = threadIdx.x;
  int jt = blockIdx.x % 9, kt = blockIdx.x / 9;
  int k0 = kt * 64;
  for (int i = tid; i < 8 * 64; i += 256) {
    int r = i >> 6, kk = i & 63;
    float scale = rsqrtf(ssq_in[r] / (float)D_ + EPSF);
    xs[r][kk] = res[r * D_ + k0 + kk] * scale * lnw[k0 + kk];
  }
  __syncthreads();
  int j = jt * 1024 + tid * 4;
  if (j >= DOUT) return;
  f32x4 acc[8];
  #pragma unroll
  for (int r = 0; r < 8; ++r) acc[r] = (f32x4)0.f;
  const float* Wp = W + (size_t)k0 * DOUT + j;
  for (int kk = 0; kk < 64; ++kk) {
    f32x4 w4 = __builtin_nontemporal_load(
        reinterpret_cast<const f32x4*>(Wp + (size_t)kk * DOUT));
    #pragma unroll
    for (int r = 0; r < 8; ++r) acc[r] += w4 * xs[r][kk];
  }
  #pragma unroll
  for (int r = 0; r < 8; ++r)
    *reinterpret_cast<f32x4*>(&pin[((size_t)kt * 8 + r) * DOUT + j]) = acc[r];
}

// ------- in_proj stage 2: reduce partials -> zx, fused conv+dt+softmax -------
__global__ __launch_bounds__(256)
void k_inproj2_conv(const float* __restrict__ pin, const float* __restrict__ conv_state,
                    const float* __restrict__ conv_w, const float* __restrict__ conv_b,
                    const float* __restrict__ A_log, const float* __restrict__ dt_bias,
                    const float* __restrict__ W_mc,
                    float* __restrict__ zx, float* __restrict__ xbc,
                    float* __restrict__ dts, float* __restrict__ dav,
                    float* __restrict__ wmc) {
  const int TOT4 = B_ * DOUT / 4;   // 17024
  int t = blockIdx.x * 256 + threadIdx.x;
  if (t >= TOT4) return;
  f32x4 s = (f32x4)0.f;
  const f32x4* p4 = reinterpret_cast<const f32x4*>(pin) + t;
  #pragma unroll 8
  for (int kt = 0; kt < KT_IN; ++kt) s += p4[(size_t)kt * TOT4];
  reinterpret_cast<f32x4*>(zx)[t] = s;
  int c4 = t * 4;
  int b = c4 / DOUT;
  int c = c4 - b * DOUT;
  #pragma unroll
  for (int e = 0; e < 4; ++e) {
    int ce = c + e;
    if (ce >= DI && ce < DI + CCH) {
      int cc = ce - DI;
      f32x4 cs4 = *reinterpret_cast<const f32x4*>(conv_state + ((size_t)b * CCH + cc) * K_);
      f32x4 cw4 = *reinterpret_cast<const f32x4*>(conv_w + (size_t)cc * K_);
      float v = cs4[1] * cw4[0] + cs4[2] * cw4[1] + cs4[3] * cw4[2]
              + s[e] * cw4[3] + conv_b[cc];
      xbc[b * CCH + cc] = v / (1.f + expf(-v));   // silu
    } else if (ce >= DI + CCH) {
      int h = ce - DI - CCH;
      float x = s[e] + dt_bias[h];
      float sp = (x > 20.f) ? x : log1pf(expf(x));  // softplus
      dts[b * 64 + h] = sp;
      dav[b * 64 + h] = expf(-expf(A_log[h]) * sp);
    }
  }
  if (t == 0) {
    float mx = -1e30f;
    for (int i = 0; i < M_ + 1; ++i) mx = fmaxf(mx, W_mc[i]);
    float e2[M_ + 1], sum = 0.f;
    for (int i = 0; i < M_ + 1; ++i) { e2[i] = expf(W_mc[i] - mx); sum += e2[i]; }
    for (int i = 0; i < M_ + 1; ++i) wmc[i] = e2[i] / sum;
  }
}

// ---------------- state update + MC fuse + y (R10-exact) ---------------------
__global__ __launch_bounds__(256)
void k_state(const float* __restrict__ xbc, const float* __restrict__ dts,
             const float* __restrict__ dav, const float* __restrict__ Dp_,
             const float* __restrict__ wmc, const float* __restrict__ ssm,
             const float* __restrict__ cached, float* __restrict__ y) {
  int wg = blockIdx.x * 4 + (threadIdx.x >> 6);   // [0, 16384)
  int lane = threadIdx.x & 63;
  int b = wg >> 11;
  int h = (wg >> 5) & 63;
  int pp = wg & 31;
  int hf = lane >> 5, il = lane & 31;
  int p = pp * 2 + hf;
  float xv  = xbc[b * CCH + h * 64 + p];
  float dtv = dts[b * 64 + h];
  float da  = dav[b * 64 + h];
  float w8  = wmc[8];
  const f32x4* xb4 = reinterpret_cast<const f32x4*>(xbc);
  f32x4 B4 = xb4[b * (CCH / 4) + DI / 4 + il];
  f32x4 C4 = xb4[b * (CCH / 4) + DI / 4 + N_ / 4 + il];
  const f32x4* sp4 = reinterpret_cast<const f32x4*>(ssm) +
                     ((size_t)((b * H_ + h) * P_ + p)) * (N_ / 4) + il;
  const f32x4* cp4 = reinterpret_cast<const f32x4*>(cached) +
                     ((size_t)(((b * M_) * H_ + h) * P_ + p)) * (N_ / 4) + il;
  f32x4 s4 = __builtin_nontemporal_load(sp4);
  f32x4 f4 = (s4 * da + B4 * (dtv * xv)) * w8;
  #pragma unroll
  for (int m = 0; m < 8; ++m) {
    f32x4 c4 = __builtin_nontemporal_load(cp4 + (size_t)m * (H_ * P_ * N_ / 4));
    f4 += c4 * wmc[m];
  }
  f4 *= C4;
  float acc = f4[0] + f4[1] + f4[2] + f4[3];
  #pragma unroll
  for (int off = 1; off < 32; off <<= 1) acc += __shfl_xor(acc, off, 64);
  if (il == 0) y[b * DI + h * 64 + p] = acc + Dp_[h] * xv;
}

// -------- gated RMS norm (R10 form) + zero ssq_in[b] for outproj2 accum ------
__global__ void k_gatednorm(const float* __restrict__ y, const float* __restrict__ zx,
                            const float* __restrict__ mnw, float* __restrict__ yg,
                            float* __restrict__ ssq_in) {
  __shared__ float lds[8];
  int b = blockIdx.x;
  if (threadIdx.x == 0) ssq_in[b] = 0.f;
  float tv[16];
  float ss = 0.f;
  #pragma unroll
  for (int t = 0; t < 16; ++t) {
    int i = threadIdx.x + t * 256;
    float z = zx[b * DOUT + i];
    float v = y[b * DI + i] * (z / (1.f + expf(-z)));
    tv[t] = v; ss += v * v;
  }
  float wsum = wave_sum(ss);
  int lane = threadIdx.x & 63, wid = threadIdx.x >> 6;
  if (lane == 0) lds[wid] = wsum;
  __syncthreads();
  float tot = lds[0] + lds[1] + lds[2] + lds[3];
  float scale = rsqrtf(tot / (float)DI + EPSF);
  #pragma unroll
  for (int t = 0; t < 16; ++t) {
    int i = threadIdx.x + t * 256;
    yg[b * DI + i] = tv[t] * scale * mnw[i];
  }
}

// ---------------- out_proj stage 1 (R10-exact): partials, no atomics ---------
__global__ void k_outproj1(const float* __restrict__ yg, const float* __restrict__ W,
                           float* __restrict__ pout) {
  __shared__ float xs[8][32];
  int jt = blockIdx.x & 1, kt = blockIdx.x >> 1;
  int k0 = kt * 32;
  for (int i = threadIdx.x; i < 8 * 32; i += 256) {
    int r = i >> 5, kk = i & 31;
    xs[r][kk] = yg[r * DI + k0 + kk];
  }
  __syncthreads();
  int j = jt * 1024 + threadIdx.x * 4;
  f32x4 acc[8];
  #pragma unroll
  for (int r = 0; r < 8; ++r) acc[r] = (f32x4)0.f;
  const float* Wp = W + (size_t)k0 * D_ + j;
  for (int kk = 0; kk < 32; ++kk) {
    f32x4 w4 = __builtin_nontemporal_load(
        reinterpret_cast<const f32x4*>(Wp + (size_t)kk * D_));
    #pragma unroll
    for (int r = 0; r < 8; ++r) acc[r] += w4 * xs[r][kk];
  }
  #pragma unroll
  for (int r = 0; r < 8; ++r)
    *reinterpret_cast<f32x4*>(&pout[((size_t)kt * 8 + r) * D_ + j]) = acc[r];
}

// ------- out_proj stage 2: reduce partials; L0 (ids): res = emb[ids]+tot,
// ------- else res += tot; accumulates next-norm ssq_in[row].
__global__ __launch_bounds__(256)
void k_outproj2(const float* __restrict__ pout, float* __restrict__ res,
                const int* __restrict__ ids, const float* __restrict__ emb,
                float* __restrict__ ssq_in) {
  __shared__ f32x4 red[256];
  const int TOT4 = B_ * D_ / 4;   // 4096
  int tid = threadIdx.x;
  int pos = blockIdx.x * 64 + (tid & 63);
  int kq = tid >> 6;              // wave index = kt quarter
  const f32x4* p4 = reinterpret_cast<const f32x4*>(pout) + pos;
  f32x4 s = (f32x4)0.f;
  #pragma unroll 8
  for (int k = 0; k < 32; ++k)
    s += p4[(size_t)(kq * 32 + k) * TOT4];
  red[tid] = s;
  __syncthreads();
  if (tid < 64) {
    f32x4 tot = red[tid] + red[tid + 64] + red[tid + 128] + red[tid + 192];
    f32x4* r4 = reinterpret_cast<f32x4*>(res);
    f32x4 nv;
    if (ids) {
      int b = pos >> 9, d4 = pos & 511;
      f32x4 base = reinterpret_cast<const f32x4*>(emb)[(size_t)ids[b] * (D_ / 4) + d4];
      nv = base + tot;
    } else {
      nv = r4[pos] + tot;
    }
    r4[pos] = nv;
    float ps = nv[0]*nv[0] + nv[1]*nv[1] + nv[2]*nv[2] + nv[3]*nv[3];
    ps = wave_sum(ps);
    if (tid == 0) atomicAdd(&ssq_in[pos >> 9], ps);
  }
}

// ---------------- logits: wave-per-row, split-D (SL=4), FUSED final norm -----
#define SL_ 4
#define KS_ (D_ / SL_)            // 512
#define NVB16 (V_ / 16)           // 3143 (exact)
__global__ __launch_bounds__(256)
void k_logits(const float* __restrict__ res, const float* __restrict__ ssq_in,
              const float* __restrict__ nfw, const float* __restrict__ emb,
              float* __restrict__ pl) {
  __shared__ f32x4 xs[8][KS_ / 4];   // 16 KB -> 8 blocks/CU, 32 waves/CU
  int s = blockIdx.x & 3, vb = blockIdx.x >> 2;
  const f32x4* res4 = reinterpret_cast<const f32x4*>(res);
  const f32x4* nfw4 = reinterpret_cast<const f32x4*>(nfw);
  for (int i = threadIdx.x; i < 8 * (KS_ / 4); i += 256) {
    int r = i >> 7, q = i & 127;
    float scale = rsqrtf(ssq_in[r] / (float)D_ + EPSF);
    xs[r][q] = res4[r * (D_ / 4) + s * (KS_ / 4) + q] * scale
             * nfw4[s * (KS_ / 4) + q];
  }
  __syncthreads();
  int wid = threadIdx.x >> 6, lane = threadIdx.x & 63;
  int v0 = vb * 16 + wid * 4;
  const f32x4* e4 = reinterpret_cast<const f32x4*>(emb);
  #pragma unroll
  for (int vv = 0; vv < 4; ++vv) {
    int v = v0 + vv;
    const f32x4* ep = e4 + (size_t)v * (D_ / 4) + s * (KS_ / 4);
    float acc[8] = {0,0,0,0,0,0,0,0};
    #pragma unroll
    for (int st = 0; st < KS_ / 256; ++st) {
      int c = st * 64 + lane;
      f32x4 e = __builtin_nontemporal_load(ep + c);
      #pragma unroll
      for (int r = 0; r < 8; ++r) {
        f32x4 x = xs[r][c];
        acc[r] += e[0]*x[0] + e[1]*x[1] + e[2]*x[2] + e[3]*x[3];
      }
    }
    float u = fold_reduce8(acc, lane);
    if (lane < 8) pl[((size_t)s * 8 + lane) * V_ + v] = u;
  }
}

// ---------------- logits combine: out = sum of 4 slice partials --------------
__global__ __launch_bounds__(256)
void k_logits2(const float* __restrict__ pl, float* __restrict__ out) {
  int v = blockIdx.x * 256 + threadIdx.x;
  if (v >= V_) return;
  int r = blockIdx.y;
  float t = pl[(size_t)r * V_ + v]
          + pl[((size_t)8  + r) * V_ + v]
          + pl[((size_t)16 + r) * V_ + v]
          + pl[((size_t)24 + r) * V_ + v];
  out[(size_t)r * V_ + v] = t;
}

extern "C" void kernel_launch(void* const* d_in, const int* in_sizes, int n_in,
                              void* d_out, int out_size, void* d_ws, size_t ws_size,
                              hipStream_t stream) {
  const int*   ids    = (const int*)  d_in[0];
  const float* emb    = (const float*)d_in[1];
  const float* inW    = (const float*)d_in[2];
  const float* convW  = (const float*)d_in[3];
  const float* convB  = (const float*)d_in[4];
  const float* Alog   = (const float*)d_in[5];
  const float* dtB    = (const float*)d_in[6];
  const float* Dpar   = (const float*)d_in[7];
  const float* mnw    = (const float*)d_in[8];
  const float* outW   = (const float*)d_in[9];
  const float* lnw    = (const float*)d_in[10];
  const float* nfw    = (const float*)d_in[11];
  const float* Wmc    = (const float*)d_in[12];
  const float* convS  = (const float*)d_in[13];
  const float* ssmS   = (const float*)d_in[14];
  const float* cached = (const float*)d_in[15];
  float* out = (float*)d_out;
  float* ws  = (float*)d_ws;

  float* res   = ws;            // 16384 floats
  float* zx    = ws + 16384;    // 68096
  float* xbc   = ws + 84480;    // 34816
  float* dts   = ws + 119296;   // 512
  float* dav   = ws + 119808;   // 512
  float* wmc   = ws + 120320;   // 64
  float* ssqi  = ws + 120384;   // 64 (8 used)
  float* y     = ws + 120448;   // 32768
  float* yg    = ws + 153216;   // 32768
  float* pin   = ws + 185984;   // 32*8*8512 = 2179072
  float* pout  = ws + 2365056;  // 128*8*2048 = 2097152
  float* pl    = ws + 4462208;  // 4*8*50288 = 1609216 -> ends 6071424 (~24.3MB)

  for (int l = 0; l < LN; ++l) {
    if (l == 0)
      k_inproj1_first<<<288, 256, 0, stream>>>(ids, emb, lnw,
                                               inW, pin);
    else
      k_inproj1<<<288, 256, 0, stream>>>(res, ssqi, lnw + (size_t)l * D_,
                                         inW + (size_t)l * D_ * DOUT, pin);
    k_inproj2_conv<<<67, 256, 0, stream>>>(pin,
        convS + (size_t)l * B_ * CCH * K_, convW + (size_t)l * CCH * K_,
        convB + (size_t)l * CCH, Alog + l * H_, dtB + l * H_, Wmc + l * (M_ + 1),
        zx, xbc, dts, dav, wmc);
    k_state<<<4096, 256, 0, stream>>>(xbc, dts, dav, Dpar + l * H_, wmc,
        ssmS + (size_t)l * B_ * H_ * P_ * N_,
        cached + (size_t)l * B_ * M_ * H_ * P_ * N_, y);
    k_gatednorm<<<8, 256, 0, stream>>>(y, zx, mnw + (size_t)l * DI, yg, ssqi);
    k_outproj1<<<256, 256, 0, stream>>>(yg, outW + (size_t)l * DI * D_, pout);
    k_outproj2<<<64, 256, 0, stream>>>(pout, res,
                                       (l == 0) ? ids : nullptr, emb, ssqi);
  }
  k_logits<<<NVB16 * SL_, 256, 0, stream>>>(res, ssqi, nfw, emb, pl);
  k_logits2<<<dim3((V_ + 255) / 256, 8), 256, 0, stream>>>(pl, out);
}